// Round 1
// baseline (207.723 us; speedup 1.0000x reference)
//
#include <hip/hip_runtime.h>

// Problem constants (fixed by setup_inputs)
#define Bdim 32
#define Ndim 64
#define Tdim 40
#define Adim 6
#define Zdim 64
#define Cdim 3
#define ROWS   (Bdim * Ndim * Tdim * Adim)   // 491520 rows of 64 floats
#define UNITS  (ROWS / 12)                   // 40960 units (1 unit = 12 rows = 2 triples)
#define NBLOCKS 1024
#define WPB     4                            // waves per block (256 threads)
#define UPW     (UNITS / (NBLOCKS * WPB))    // 10 units per wave, exact

// logits[b,n,t,a] = dot(df[b,n,t,a,:], z[b,n,:]) + u[b,n,t,a] - feas_mean_a(u)
// Frenet term is constant over (t,a) and cancels in (u - u_mean) ->
// map_polylines/idx/pts are dead inputs.
//
// Structure: persistent streaming waves, NO __syncthreads, NO LDS.
// Each wave owns UPW contiguous units; 1-deep software pipeline keeps the
// next unit's loads (3x dwordx4 df + z + ctx + feas) in flight while the
// current unit computes. Epilogue is wave-local via ds_bpermute + shfl_xor.

template <int CTRL>
__device__ __forceinline__ float dpp_shr_add(float v) {
    int s = __builtin_amdgcn_update_dpp(0, __float_as_int(v), CTRL, 0xF, 0xF, true);
    return v + __int_as_float(s);
}

__global__ __launch_bounds__(256) void mpd_stream_kernel(
    const float* __restrict__ df,    // (B,N,T,A,Z)
    const float* __restrict__ z,     // (B,N,Z)
    const float* __restrict__ ctx,   // (B,N,T,A,C)
    const int*   __restrict__ feas,  // (B,N,T,A)
    const float* __restrict__ w,     // (C,)
    const float* __restrict__ b0,    // (1,)
    float*       __restrict__ out)   // (B,N,T,A)
{
    const int tid    = threadIdx.x;
    const int lane   = tid & 63;
    const int waveId = blockIdx.x * WPB + (tid >> 6);
    const int unit0  = waveId * UPW;

    // Uniform scalars (hoisted; compiler emits s_loads)
    const float w0 = w[0], w1 = w[1], w2 = w[2], bb = b0[0];

    // Epilogue lane mapping: lanes 0..15, two octets; a = lane&7, triple = lane>>3
    const int  a    = lane & 7;
    const int  tri  = lane >> 3;
    const bool act  = (lane < 16) && (a < Adim);
    const int  erow = tri * Adim + ((a < Adim) ? a : 0);  // 0..11 (clamped if inactive)
    const int  esel = erow >> 2;                // which of p0/p1/p2 holds this row
    const int  esrc = ((erow & 3) << 4) + 15;   // lane holding that row's sum

    // ---------------- prologue: load unit0 ----------------
    float4 f0, f1, f2, z4;
    float  c0 = 0.f, c1 = 0.f, c2 = 0.f, fA = 0.f;
    {
        const float* dp = df + (size_t)unit0 * (12 * Zdim);
        f0 = *reinterpret_cast<const float4*>(dp + lane * 4);
        f1 = *reinterpret_cast<const float4*>(dp + 256 + lane * 4);
        f2 = *reinterpret_cast<const float4*>(dp + 512 + lane * 4);
        z4 = *reinterpret_cast<const float4*>(z + (unit0 / 20) * Zdim + (lane & 15) * 4);
        if (act) {
            const float* cp = ctx + ((size_t)unit0 * 12 + erow) * Cdim;
            c0 = cp[0]; c1 = cp[1]; c2 = cp[2];
            fA = (feas[unit0 * 12 + erow] != 0) ? 1.0f : 0.0f;
        }
    }

#pragma unroll 1
    for (int u = 0; u < UPW; ++u) {
        const int unit = unit0 + u;

        // current-stage registers (renames; freed as f*/z4 are overwritten)
        const float4 g0 = f0, g1 = f1, g2 = f2, zz = z4;
        const float  d0 = c0, d1 = c1, d2 = c2, fcur = fA;

        // ---- prefetch next unit (issued before any wait on current) ----
        if (u + 1 < UPW) {
            const int nu = unit + 1;
            const float* dp = df + (size_t)nu * (12 * Zdim);
            f0 = *reinterpret_cast<const float4*>(dp + lane * 4);
            f1 = *reinterpret_cast<const float4*>(dp + 256 + lane * 4);
            f2 = *reinterpret_cast<const float4*>(dp + 512 + lane * 4);
            z4 = *reinterpret_cast<const float4*>(z + (nu / 20) * Zdim + (lane & 15) * 4);
            if (act) {
                const float* cp = ctx + ((size_t)nu * 12 + erow) * Cdim;
                c0 = cp[0]; c1 = cp[1]; c2 = cp[2];
                fA = (feas[nu * 12 + erow] != 0) ? 1.0f : 0.0f;
            }
        }

        // ---- dot: 16 lanes per row, 3 row-groups of 4 rows ----
        float p0 = g0.x * zz.x + g0.y * zz.y + g0.z * zz.z + g0.w * zz.w;
        float p1 = g1.x * zz.x + g1.y * zz.y + g1.z * zz.z + g1.w * zz.w;
        float p2 = g2.x * zz.x + g2.y * zz.y + g2.z * zz.z + g2.w * zz.w;

        p0 = dpp_shr_add<0x111>(p0); p0 = dpp_shr_add<0x112>(p0);
        p0 = dpp_shr_add<0x114>(p0); p0 = dpp_shr_add<0x118>(p0);
        p1 = dpp_shr_add<0x111>(p1); p1 = dpp_shr_add<0x112>(p1);
        p1 = dpp_shr_add<0x114>(p1); p1 = dpp_shr_add<0x118>(p1);
        p2 = dpp_shr_add<0x111>(p2); p2 = dpp_shr_add<0x112>(p2);
        p2 = dpp_shr_add<0x114>(p2); p2 = dpp_shr_add<0x118>(p2);
        // row r sum now in lane ((r&3)<<4)+15 of register p[r>>2]

        // ---- gather row sums into epilogue lanes (wave-local, no LDS) ----
        const float s0 = __shfl(p0, esrc, 64);
        const float s1 = __shfl(p1, esrc, 64);
        const float s2 = __shfl(p2, esrc, 64);
        const float dsum = (esel == 0) ? s0 : ((esel == 1) ? s1 : s2);

        float uu = 0.f, fv = 0.f;
        if (act) {
            uu = d0 * w0 + d1 * w1 + d2 * w2 + bb;
            fv = fcur;
        }
        // Octet reduce over the 6 actions (inactive lanes contribute 0)
        float uf = uu * fv, fs = fv, ua = uu;
        uf += __shfl_xor(uf, 1, 64); fs += __shfl_xor(fs, 1, 64); ua += __shfl_xor(ua, 1, 64);
        uf += __shfl_xor(uf, 2, 64); fs += __shfl_xor(fs, 2, 64); ua += __shfl_xor(ua, 2, 64);
        uf += __shfl_xor(uf, 4, 64); fs += __shfl_xor(fs, 4, 64); ua += __shfl_xor(ua, 4, 64);

        // No feasible action -> all treated feasible (mean of all 6)
        const float mean = (fs > 0.5f) ? (uf / fs) : (ua * (1.0f / 6.0f));

        if (act)
            out[unit * 12 + erow] = dsum + (uu - mean);
    }
}

extern "C" void kernel_launch(void* const* d_in, const int* in_sizes, int n_in,
                              void* d_out, int out_size, void* d_ws, size_t ws_size,
                              hipStream_t stream) {
    // Inputs: map_polylines(0), idx(1), pts(2), z(3), decision_features(4),
    //         ctx_features(5), feasible_actions(6), u_ctx_w(7), u_ctx_b(8)
    const float* z    = (const float*)d_in[3];
    const float* df   = (const float*)d_in[4];
    const float* ctx  = (const float*)d_in[5];
    const int*   feas = (const int*)  d_in[6];
    const float* w    = (const float*)d_in[7];
    const float* b0   = (const float*)d_in[8];
    float* out = (float*)d_out;

    mpd_stream_kernel<<<NBLOCKS, 256, 0, stream>>>(df, z, ctx, feas, w, b0, out);
}

// Round 2
// 200.353 us; speedup vs baseline: 1.0368x; 1.0368x over previous
//
#include <hip/hip_runtime.h>

// Problem constants (fixed by setup_inputs)
#define Bdim 32
#define Ndim 64
#define Tdim 40
#define Adim 6
#define Zdim 64
#define Cdim 3
#define ROWS   (Bdim * Ndim * Tdim * Adim)   // 491520 rows of 64 floats (df = 125.8 MB)
#define UNITS  (ROWS / 12)                   // 40960 units (1 unit = 12 rows = 2 triples)
#define WPB    4                             // waves per block (256 threads)
#define NBLOCKS (UNITS / WPB)                // 10240 blocks, 1 unit per wave

// logits[b,n,t,a] = dot(df[b,n,t,a,:], z[b,n,:]) + u[b,n,t,a] - feas_mean_a(u)
// Frenet term is constant over (t,a) and cancels in (u - u_mean) ->
// map_polylines/idx/pts are dead inputs.
//
// Structure: one-shot waves (max TLP: 40960 waves, 32 waves/CU) with ALL
// loads (3x df dwordx4 + z + ctx + feas) issued up front in a single
// latency round. No LDS, no __syncthreads: the epilogue is wave-local
// (shfl gather of row sums + octet shfl_xor reduce over the 6 actions).

template <int CTRL>
__device__ __forceinline__ float dpp_shr_add(float v) {
    int s = __builtin_amdgcn_update_dpp(0, __float_as_int(v), CTRL, 0xF, 0xF, true);
    return v + __int_as_float(s);
}

__global__ __launch_bounds__(256) void mpd_oneshot_kernel(
    const float* __restrict__ df,    // (B,N,T,A,Z)
    const float* __restrict__ z,     // (B,N,Z)
    const float* __restrict__ ctx,   // (B,N,T,A,C)
    const int*   __restrict__ feas,  // (B,N,T,A)
    const float* __restrict__ w,     // (C,)
    const float* __restrict__ b0,    // (1,)
    float*       __restrict__ out)   // (B,N,T,A)
{
    const int tid  = threadIdx.x;
    const int lane = tid & 63;
    const int unit = blockIdx.x * WPB + (tid >> 6);   // one 12-row unit per wave

    // Epilogue lane mapping: lanes 0..15, two octets; a = lane&7, triple = lane>>3
    const int  a    = lane & 7;
    const int  tri  = lane >> 3;
    const bool act  = (lane < 16) && (a < Adim);
    const int  erow = tri * Adim + ((a < Adim) ? a : 0);  // 0..11 (clamped if inactive)
    const int  esel = erow >> 2;                 // which of p0/p1/p2 holds this row
    const int  esrc = ((erow & 3) << 4) + 15;    // lane holding that row's sum

    // ---- issue ALL global loads up front (single latency round) ----
    const float* dp = df + (size_t)unit * (12 * Zdim);
    const float4 f0 = *reinterpret_cast<const float4*>(dp + lane * 4);
    const float4 f1 = *reinterpret_cast<const float4*>(dp + 256 + lane * 4);
    const float4 f2 = *reinterpret_cast<const float4*>(dp + 512 + lane * 4);
    const float4 z4 = *reinterpret_cast<const float4*>(
        z + (unit / 20) * Zdim + (lane & 15) * 4);   // 20 units per (b,n)

    float c0 = 0.f, c1 = 0.f, c2 = 0.f, fv = 0.f;
    if (act) {
        const float* cp = ctx + ((size_t)unit * 12 + erow) * Cdim;
        c0 = cp[0]; c1 = cp[1]; c2 = cp[2];
        fv = (feas[unit * 12 + erow] != 0) ? 1.0f : 0.0f;
    }
    const float w0 = w[0], w1 = w[1], w2 = w[2], bb = b0[0];

    // ---- dot: 16 lanes per row, 3 register-groups of 4 rows ----
    float p0 = f0.x * z4.x + f0.y * z4.y + f0.z * z4.z + f0.w * z4.w;
    float p1 = f1.x * z4.x + f1.y * z4.y + f1.z * z4.z + f1.w * z4.w;
    float p2 = f2.x * z4.x + f2.y * z4.y + f2.z * z4.z + f2.w * z4.w;

    p0 = dpp_shr_add<0x111>(p0); p0 = dpp_shr_add<0x112>(p0);
    p0 = dpp_shr_add<0x114>(p0); p0 = dpp_shr_add<0x118>(p0);
    p1 = dpp_shr_add<0x111>(p1); p1 = dpp_shr_add<0x112>(p1);
    p1 = dpp_shr_add<0x114>(p1); p1 = dpp_shr_add<0x118>(p1);
    p2 = dpp_shr_add<0x111>(p2); p2 = dpp_shr_add<0x112>(p2);
    p2 = dpp_shr_add<0x114>(p2); p2 = dpp_shr_add<0x118>(p2);
    // row r sum now in lane ((r&3)<<4)+15 of register p[r>>2]

    // ---- gather row sums into epilogue lanes (wave-local, no LDS) ----
    const float s0 = __shfl(p0, esrc, 64);
    const float s1 = __shfl(p1, esrc, 64);
    const float s2 = __shfl(p2, esrc, 64);
    const float dsum = (esel == 0) ? s0 : ((esel == 1) ? s1 : s2);

    float uu = 0.f;
    if (act)
        uu = c0 * w0 + c1 * w1 + c2 * w2 + bb;

    // Octet reduce over the 6 actions (inactive lanes contribute 0)
    float uf = uu * fv, fs = fv, ua = uu;
    uf += __shfl_xor(uf, 1, 64); fs += __shfl_xor(fs, 1, 64); ua += __shfl_xor(ua, 1, 64);
    uf += __shfl_xor(uf, 2, 64); fs += __shfl_xor(fs, 2, 64); ua += __shfl_xor(ua, 2, 64);
    uf += __shfl_xor(uf, 4, 64); fs += __shfl_xor(fs, 4, 64); ua += __shfl_xor(ua, 4, 64);

    // No feasible action -> all treated feasible (mean of all 6)
    const float mean = (fs > 0.5f) ? (uf / fs) : (ua * (1.0f / 6.0f));

    if (act)
        out[unit * 12 + erow] = dsum + (uu - mean);
}

extern "C" void kernel_launch(void* const* d_in, const int* in_sizes, int n_in,
                              void* d_out, int out_size, void* d_ws, size_t ws_size,
                              hipStream_t stream) {
    // Inputs: map_polylines(0), idx(1), pts(2), z(3), decision_features(4),
    //         ctx_features(5), feasible_actions(6), u_ctx_w(7), u_ctx_b(8)
    const float* z    = (const float*)d_in[3];
    const float* df   = (const float*)d_in[4];
    const float* ctx  = (const float*)d_in[5];
    const int*   feas = (const int*)  d_in[6];
    const float* w    = (const float*)d_in[7];
    const float* b0   = (const float*)d_in[8];
    float* out = (float*)d_out;

    mpd_oneshot_kernel<<<NBLOCKS, 256, 0, stream>>>(df, z, ctx, feas, w, b0, out);
}